// Round 1
// baseline (412.812 us; speedup 1.0000x reference)
//
#include <hip/hip_runtime.h>
#include <hip/hip_bf16.h>

#define NB 16
#define NS 2048
#define ND 768
#define NG 1024
#define ROWS (NB * NG)            // 16384 output rows (b*G + g)

typedef __attribute__((ext_vector_type(8))) __bf16 bf16x8;
typedef __attribute__((ext_vector_type(8))) unsigned short ushort8_t;
typedef __attribute__((ext_vector_type(4))) unsigned short ushort4_t;
typedef __attribute__((ext_vector_type(4))) float f32x4;

__device__ __forceinline__ unsigned short f2bf(float f) {
    unsigned int u = __builtin_bit_cast(unsigned int, f);
    return (unsigned short)((u + 0x7FFFu + ((u >> 16) & 1u)) >> 16);   // RNE
}

// ---- pair-mean over tokens + cast to bf16: mean[b*G+g][d] = 0.5*(x[b][2g][d]+x[b][2g+1][d])
__global__ __launch_bounds__(256) void mean_cast_kernel(const float* __restrict__ x,
                                                        unsigned short* __restrict__ mbf) {
    int i = blockIdx.x * 256 + threadIdx.x;      // over ROWS*ND/4 = 3145728
    int e = i * 4;
    int b = e / (NG * ND);
    int rem = e - b * (NG * ND);
    int g = rem / ND;
    int d = rem - g * ND;
    const float* p0 = x + ((long)(b * NS + 2 * g) * ND + d);
    float4 a0 = *(const float4*)p0;
    float4 a1 = *(const float4*)(p0 + ND);
    ushort4_t o;
    o.x = f2bf(0.5f * (a0.x + a1.x));
    o.y = f2bf(0.5f * (a0.y + a1.y));
    o.z = f2bf(0.5f * (a0.z + a1.z));
    o.w = f2bf(0.5f * (a0.w + a1.w));
    *(ushort4_t*)(mbf + e) = o;
}

// ---- cast W (768x768 f32, row-major) to bf16
__global__ __launch_bounds__(256) void wcast_kernel(const float* __restrict__ W,
                                                    unsigned short* __restrict__ wbf) {
    int i = blockIdx.x * 256 + threadIdx.x;      // over ND*ND/4 = 147456
    int e = i * 4;
    float4 a = *(const float4*)(W + e);
    ushort4_t o;
    o.x = f2bf(a.x); o.y = f2bf(a.y); o.z = f2bf(a.z); o.w = f2bf(a.w);
    *(ushort4_t*)(wbf + e) = o;
}

// ---- GEMM: out[r][c] = tanh( sum_k mean[r][k] * W[k][c] + bias[c] )
// one wave per 16x16 tile; 4 waves/block cover 16 rows x 64 cols.
// mfma_f32_16x16x32_bf16 fragment layout (m89/m91-verified):
//   A: row = lane&15, k = 8*(lane>>4) + j (j=0..7 contiguous)
//   B: col = lane&15, k = 8*(lane>>4) + j
//   C/D: col = lane&15, row = 4*(lane>>4) + reg
__global__ __launch_bounds__(256) void gemm_tanh_kernel(const unsigned short* __restrict__ Abf,
                                                        const unsigned short* __restrict__ Bbf,
                                                        const float* __restrict__ bias,
                                                        float* __restrict__ out) {
    int w = threadIdx.x >> 6;
    int lane = threadIdx.x & 63;
    int row0 = blockIdx.x * 16;
    int col0 = blockIdx.y * 64 + w * 16;
    int r = lane & 15;
    int h = lane >> 4;

    const unsigned short* arow = Abf + (long)(row0 + r) * ND + h * 8;
    const unsigned short* bcol = Bbf + (long)(h * 8) * ND + col0 + r;

    f32x4 acc = {0.f, 0.f, 0.f, 0.f};
    #pragma unroll 4
    for (int k0 = 0; k0 < ND; k0 += 32) {
        bf16x8 a = __builtin_bit_cast(bf16x8, *(const ushort8_t*)arow);
        ushort8_t bu;
        #pragma unroll
        for (int j = 0; j < 8; ++j) bu[j] = bcol[(long)j * ND];
        bf16x8 bb = __builtin_bit_cast(bf16x8, bu);
        acc = __builtin_amdgcn_mfma_f32_16x16x32_bf16(a, bb, acc, 0, 0, 0);
        arow += 32;
        bcol += (long)32 * ND;
    }
    float bs = bias[col0 + r];
    #pragma unroll
    for (int q = 0; q < 4; ++q) {
        int orow = row0 + h * 4 + q;
        out[(long)orow * ND + col0 + r] = tanhf(acc[q] + bs);
    }
}

// ---- per-group masks (each group = tokens 2g, 2g+1), written as float32
__global__ __launch_bounds__(256) void masks_kernel(const int* __restrict__ padding,
                                                    const int* __restrict__ regular,
                                                    const int* __restrict__ seqpair,
                                                    float* __restrict__ out_mp,
                                                    float* __restrict__ out_mr,
                                                    float* __restrict__ out_ms) {
    int i = blockIdx.x * 256 + threadIdx.x;      // over ROWS
    int b = i / NG;
    int g = i - b * NG;
    int t = b * NS + 2 * g;
    int p  = ((padding[t] | padding[t + 1]) != 0) ? 1 : 0;
    int mr = ((regular[t] | regular[t + 1]) != 0) ? 1 : 0;
    int ms = ((seqpair[t] > 0) && (seqpair[t + 1] > 0)) ? 1 : 0;
    if (p == 0) ms = -1;
    out_mp[i] = (float)p;
    out_mr[i] = (float)mr;
    out_ms[i] = (float)ms;
}

// ---- compression_rate = sum(mask_regular) / sum(regular_tokens_mask)
__global__ __launch_bounds__(256) void finalize_kernel(const float* __restrict__ mr,
                                                       const int* __restrict__ regular,
                                                       float* __restrict__ cr) {
    __shared__ float s_m[256];
    __shared__ int s_t[256];
    float am = 0.f;
    int at = 0;
    for (int i = threadIdx.x; i < ROWS; i += 256) am += mr[i];
    for (int i = threadIdx.x; i < NB * NS; i += 256) at += regular[i];
    s_m[threadIdx.x] = am;
    s_t[threadIdx.x] = at;
    __syncthreads();
    for (int off = 128; off > 0; off >>= 1) {
        if (threadIdx.x < off) {
            s_m[threadIdx.x] += s_m[threadIdx.x + off];
            s_t[threadIdx.x] += s_t[threadIdx.x + off];
        }
        __syncthreads();
    }
    if (threadIdx.x == 0) cr[0] = s_m[0] / (float)s_t[0];
}

extern "C" void kernel_launch(void* const* d_in, const int* in_sizes, int n_in,
                              void* d_out, int out_size, void* d_ws, size_t ws_size,
                              hipStream_t stream) {
    const float* x        = (const float*)d_in[0];
    // d_in[1] = group_ids (structure is fixed pairs: group j//2) — unused
    const int*   padding  = (const int*)d_in[2];
    const int*   regular  = (const int*)d_in[3];
    const int*   seqpair  = (const int*)d_in[4];
    // d_in[5] = num_groups scalar — unused
    const float* W        = (const float*)d_in[6];
    const float* bias     = (const float*)d_in[7];

    float* outc   = (float*)d_out;                       // compact (B,G,D)
    float* out_mp = outc + (long)ROWS * ND;              // mask_padding (B,G)
    float* out_mr = out_mp + ROWS;                       // mask_regular (B,G)
    float* out_ms = out_mr + ROWS;                       // mask_seq_pair (B,G)
    float* out_cr = out_ms + ROWS;                       // compression_rate (1)

    unsigned short* mbf = (unsigned short*)d_ws;                          // 16384*768*2 = 25165824 B
    unsigned short* wbf = (unsigned short*)((char*)d_ws + 25165824);      // 768*768*2  =  1179648 B

    wcast_kernel<<<(ND * ND / 4 + 255) / 256, 256, 0, stream>>>(W, wbf);
    mean_cast_kernel<<<(ROWS * ND / 4 + 255) / 256, 256, 0, stream>>>(x, mbf);
    gemm_tanh_kernel<<<dim3(ROWS / 16, ND / 64), 256, 0, stream>>>(mbf, wbf, bias, outc);
    masks_kernel<<<ROWS / 256, 256, 0, stream>>>(padding, regular, seqpair, out_mp, out_mr, out_ms);
    finalize_kernel<<<1, 256, 0, stream>>>(out_mr, regular, out_cr);
}

// Round 2
// 209.705 us; speedup vs baseline: 1.9685x; 1.9685x over previous
//
#include <hip/hip_runtime.h>
#include <hip/hip_bf16.h>

#define NB 16
#define NS 2048
#define ND 768
#define NG 1024
#define ROWS (NB * NG)            // 16384 output rows (b*G + g)

#define BM 128
#define BN 128
#define BK 32

typedef __attribute__((ext_vector_type(8))) __bf16 bf16x8;
typedef __attribute__((ext_vector_type(8))) unsigned short ushort8_t;
typedef __attribute__((ext_vector_type(4))) unsigned short ushort4_t;
typedef __attribute__((ext_vector_type(4))) float f32x4;

__device__ __forceinline__ unsigned short f2bf(float f) {
    unsigned int u = __builtin_bit_cast(unsigned int, f);
    return (unsigned short)((u + 0x7FFFu + ((u >> 16) & 1u)) >> 16);   // RNE
}

__device__ __forceinline__ void gload_lds16(const void* g, void* l) {
    __builtin_amdgcn_global_load_lds((const __attribute__((address_space(1))) unsigned int*)g,
                                     (__attribute__((address_space(3))) unsigned int*)l, 16, 0, 0);
}

// ---- pair-mean over tokens + cast to bf16: mean[b*G+g][d] = 0.5*(x[b][2g][d]+x[b][2g+1][d])
__global__ __launch_bounds__(256) void mean_cast_kernel(const float* __restrict__ x,
                                                        unsigned short* __restrict__ mbf) {
    int i = blockIdx.x * 256 + threadIdx.x;      // over ROWS*ND/4 = 3145728
    int e = i * 4;
    int b = e / (NG * ND);
    int rem = e - b * (NG * ND);
    int g = rem / ND;
    int d = rem - g * ND;
    const float* p0 = x + ((long)(b * NS + 2 * g) * ND + d);
    float4 a0 = *(const float4*)p0;
    float4 a1 = *(const float4*)(p0 + ND);
    ushort4_t o;
    o.x = f2bf(0.5f * (a0.x + a1.x));
    o.y = f2bf(0.5f * (a0.y + a1.y));
    o.z = f2bf(0.5f * (a0.z + a1.z));
    o.w = f2bf(0.5f * (a0.w + a1.w));
    *(ushort4_t*)(mbf + e) = o;
}

// ---- transpose-cast W (768x768 f32 row-major [k][n]) to bf16 [n][k]
__global__ __launch_bounds__(256) void wtrans_kernel(const float* __restrict__ W,
                                                     unsigned short* __restrict__ Bt) {
    __shared__ float tile[64][65];
    int n0 = blockIdx.x * 64;
    int k0 = blockIdx.y * 64;
    int tx = threadIdx.x & 63;
    int ty = threadIdx.x >> 6;    // 0..3
    #pragma unroll
    for (int i = 0; i < 64; i += 4)
        tile[ty + i][tx] = W[(long)(k0 + ty + i) * ND + n0 + tx];
    __syncthreads();
    #pragma unroll
    for (int i = 0; i < 64; i += 4)
        Bt[(long)(n0 + ty + i) * ND + k0 + tx] = f2bf(tile[tx][ty + i]);
}

// ---- GEMM: out[r][c] = tanh( sum_k A[r][k] * Bt[c][k] + bias[c] )
// 128x128 tile, BK=32, 4 waves (2x2), each wave 64x64 = 4x4 fragments of 16x16x32.
// A-frag: row=lane&15, k=8*(lane>>4)+j ; C/D: col=lane&15, row=4*(lane>>4)+reg (verified R0).
__global__ __launch_bounds__(256) void gemm_tanh_kernel(const unsigned short* __restrict__ A,
                                                        const unsigned short* __restrict__ Bt,
                                                        const float* __restrict__ bias,
                                                        float* __restrict__ out) {
    __shared__ unsigned short Al[BM * BK];   // [128][32]
    __shared__ unsigned short Bl[BN * BK];   // [128][32]  (row = n, col = k)
    int tid = threadIdx.x;
    int lane = tid & 63;
    int w = tid >> 6;
    int wr = w >> 1, wc = w & 1;
    int row0 = blockIdx.x * BM;
    int col0 = blockIdx.y * BN;
    int r = lane & 15, h = lane >> 4;

    // staging: linear 16B chunk idx = q*256+tid; row=idx>>2, colbyte=(idx&3)*16
    const char* gA0 = (const char*)A  + ((long)(row0 + (tid >> 2)) * ND + (tid & 3) * 8) * 2;
    const char* gB0 = (const char*)Bt + ((long)(col0 + (tid >> 2)) * ND + (tid & 3) * 8) * 2;
    const char* gA1 = gA0 + (long)64 * ND * 2;
    const char* gB1 = gB0 + (long)64 * ND * 2;
    char* lA0 = (char*)Al + tid * 16;
    char* lB0 = (char*)Bl + tid * 16;
    char* lA1 = lA0 + 4096;
    char* lB1 = lB0 + 4096;

    f32x4 acc[4][4] = {};

    for (int k0 = 0; k0 < ND; k0 += BK) {
        gload_lds16(gA0, lA0);
        gload_lds16(gA1, lA1);
        gload_lds16(gB0, lB0);
        gload_lds16(gB1, lB1);
        gA0 += BK * 2; gA1 += BK * 2; gB0 += BK * 2; gB1 += BK * 2;
        __syncthreads();                     // compiler drains vmcnt before barrier

        bf16x8 af[4], bfr[4];
        #pragma unroll
        for (int m = 0; m < 4; ++m)
            af[m] = __builtin_bit_cast(bf16x8, *(const ushort8_t*)&Al[(wr * 64 + m * 16 + r) * BK + h * 8]);
        #pragma unroll
        for (int n = 0; n < 4; ++n)
            bfr[n] = __builtin_bit_cast(bf16x8, *(const ushort8_t*)&Bl[(wc * 64 + n * 16 + r) * BK + h * 8]);
        #pragma unroll
        for (int m = 0; m < 4; ++m)
            #pragma unroll
            for (int n = 0; n < 4; ++n)
                acc[m][n] = __builtin_amdgcn_mfma_f32_16x16x32_bf16(af[m], bfr[n], acc[m][n], 0, 0, 0);
        __syncthreads();
    }

    float bv[4];
    #pragma unroll
    for (int n = 0; n < 4; ++n) bv[n] = bias[col0 + wc * 64 + n * 16 + r];

    #pragma unroll
    for (int m = 0; m < 4; ++m) {
        #pragma unroll
        for (int q = 0; q < 4; ++q) {
            int orow = row0 + wr * 64 + m * 16 + h * 4 + q;
            float* op = out + (long)orow * ND + col0 + wc * 64 + r;
            #pragma unroll
            for (int n = 0; n < 4; ++n)
                op[n * 16] = tanhf(acc[m][n][q] + bv[n]);
        }
    }
}

// ---- per-group masks + fused sums for compression rate
__global__ __launch_bounds__(256) void masks_kernel(const int* __restrict__ padding,
                                                    const int* __restrict__ regular,
                                                    const int* __restrict__ seqpair,
                                                    float* __restrict__ out_mp,
                                                    float* __restrict__ out_mr,
                                                    float* __restrict__ out_ms,
                                                    int* __restrict__ sums) {
    int i = blockIdx.x * 256 + threadIdx.x;      // over ROWS
    int b = i >> 10, g = i & (NG - 1);
    int t = b * NS + 2 * g;
    int r0 = regular[t], r1 = regular[t + 1];
    int p  = ((padding[t] | padding[t + 1]) != 0) ? 1 : 0;
    int mr = ((r0 | r1) != 0) ? 1 : 0;
    int ms = ((seqpair[t] > 0) && (seqpair[t + 1] > 0)) ? 1 : 0;
    if (p == 0) ms = -1;
    out_mp[i] = (float)p;
    out_mr[i] = (float)mr;
    out_ms[i] = (float)ms;

    int mrs = mr, tok = r0 + r1;
    #pragma unroll
    for (int off = 32; off > 0; off >>= 1) {
        mrs += __shfl_down(mrs, off);
        tok += __shfl_down(tok, off);
    }
    __shared__ int sm[4], st[4];
    int wv = threadIdx.x >> 6, lane = threadIdx.x & 63;
    if (lane == 0) { sm[wv] = mrs; st[wv] = tok; }
    __syncthreads();
    if (threadIdx.x == 0) {
        atomicAdd(&sums[0], sm[0] + sm[1] + sm[2] + sm[3]);
        atomicAdd(&sums[1], st[0] + st[1] + st[2] + st[3]);
    }
}

__global__ void zero_kernel(int* __restrict__ s) { if (threadIdx.x < 2) s[threadIdx.x] = 0; }

__global__ void div_kernel(const int* __restrict__ s, float* __restrict__ cr) {
    cr[0] = (float)s[0] / (float)s[1];
}

extern "C" void kernel_launch(void* const* d_in, const int* in_sizes, int n_in,
                              void* d_out, int out_size, void* d_ws, size_t ws_size,
                              hipStream_t stream) {
    const float* x        = (const float*)d_in[0];
    const int*   padding  = (const int*)d_in[2];
    const int*   regular  = (const int*)d_in[3];
    const int*   seqpair  = (const int*)d_in[4];
    const float* W        = (const float*)d_in[6];
    const float* bias     = (const float*)d_in[7];

    float* outc   = (float*)d_out;                       // compact (B,G,D)
    float* out_mp = outc + (long)ROWS * ND;              // mask_padding (B,G)
    float* out_mr = out_mp + ROWS;                       // mask_regular (B,G)
    float* out_ms = out_mr + ROWS;                       // mask_seq_pair (B,G)
    float* out_cr = out_ms + ROWS;                       // compression_rate (1)

    unsigned short* mbf = (unsigned short*)d_ws;                          // 25165824 B
    unsigned short* wbt = (unsigned short*)((char*)d_ws + 25165824);      // 1179648 B
    int* sums = (int*)((char*)d_ws + 25165824 + 1179648);                 // 8 B

    zero_kernel<<<1, 64, 0, stream>>>(sums);
    wtrans_kernel<<<dim3(ND / 64, ND / 64), 256, 0, stream>>>(W, wbt);
    mean_cast_kernel<<<(ROWS * ND / 4 + 255) / 256, 256, 0, stream>>>(x, mbf);
    gemm_tanh_kernel<<<dim3(ROWS / BM, ND / BN), 256, 0, stream>>>(mbf, wbt, bias, outc);
    masks_kernel<<<ROWS / 256, 256, 0, stream>>>(padding, regular, seqpair, out_mp, out_mr, out_ms, sums);
    div_kernel<<<1, 1, 0, stream>>>(sums, out_cr);
}